// Round 4
// baseline (550.902 us; speedup 1.0000x reference)
//
#include <hip/hip_runtime.h>
#include <stdint.h>

#define T_TOK 8192
#define DIM   1024
#define HID   2048
#define NE    8

#define BM 128
#define BN 128
#define BK 32

#define GB_TOK 32  // tokens per gate block

typedef float floatx4 __attribute__((ext_vector_type(4)));
typedef short shortx8 __attribute__((ext_vector_type(8)));

typedef __attribute__((address_space(3))) void       lds_void;
typedef const __attribute__((address_space(1))) void gbl_void;

__device__ __forceinline__ unsigned short f2bf(float f) {
  unsigned int u = __float_as_uint(f);
  unsigned int r = 0x7fffu + ((u >> 16) & 1u);
  return (unsigned short)((u + r) >> 16);
}

// ------------- transpose+cast: in [R][C] f32 -> out [C][R] bf16, blockIdx.z = expert -------------
__global__ __launch_bounds__(256) void transpose_cast_kernel(const float* __restrict__ in,
                                                             unsigned short* __restrict__ out,
                                                             int R, int C) {
  __shared__ float tile[32][33];
  const size_t eoff = (size_t)blockIdx.z * R * C;
  const float* ip = in + eoff;
  unsigned short* op = out + eoff;
  int c0 = blockIdx.x * 32, r0 = blockIdx.y * 32;
  int tx = threadIdx.x, ty = threadIdx.y;
#pragma unroll
  for (int i = 0; i < 4; i++)
    tile[ty + i * 8][tx] = ip[(size_t)(r0 + ty + i * 8) * C + (c0 + tx)];
  __syncthreads();
#pragma unroll
  for (int i = 0; i < 4; i++)
    op[(size_t)(c0 + ty + i * 8) * R + (r0 + tx)] = f2bf(tile[tx][ty + i * 8]);
}

// ---------------- gating: 32 tokens/block; also casts x -> bf16 ----------------
__global__ __launch_bounds__(256) void gate_kernel(const float* __restrict__ x,
                                                   const float* __restrict__ wg,
                                                   unsigned short* __restrict__ xb,
                                                   int* counts, int* top1cnt, float* ssum,
                                                   int* tok_list, float* wgt_list) {
  __shared__ int   lds_cnt[8];
  __shared__ int   lds_top1[8];
  __shared__ float lds_ssum[4][8];
  __shared__ int   tk_e[GB_TOK][2];
  __shared__ int   tk_r[GB_TOK][2];
  __shared__ float tk_w[GB_TOK][2];
  __shared__ int   base[8];

  const int tid = threadIdx.x;
  const int wave = tid >> 6;
  const int lane = tid & 63;

  if (tid < 8) { lds_cnt[tid] = 0; lds_top1[tid] = 0; }
  if (tid < 32) lds_ssum[tid >> 3][tid & 7] = 0.f;
  __syncthreads();

  float ssum_local[8];
#pragma unroll
  for (int e = 0; e < 8; e++) ssum_local[e] = 0.f;

  for (int it = 0; it < GB_TOK / 4; it++) {
    const int lt = it * 4 + wave;
    const int t = blockIdx.x * GB_TOK + lt;

    float acc[8];
#pragma unroll
    for (int e = 0; e < 8; e++) acc[e] = 0.f;
    const float* xr = x + (size_t)t * DIM;
    unsigned short* xw = xb + (size_t)t * DIM;
#pragma unroll
    for (int i = 0; i < 16; i++) {
      int d = i * 64 + lane;
      float xv = xr[d];
      xw[d] = f2bf(xv);  // fused f32->bf16 cast
      const float4* wr = reinterpret_cast<const float4*>(wg + d * 8);
      float4 w0 = wr[0], w1 = wr[1];
      acc[0] += xv * w0.x; acc[1] += xv * w0.y; acc[2] += xv * w0.z; acc[3] += xv * w0.w;
      acc[4] += xv * w1.x; acc[5] += xv * w1.y; acc[6] += xv * w1.z; acc[7] += xv * w1.w;
    }
#pragma unroll
    for (int e = 0; e < 8; e++) {
#pragma unroll
      for (int off = 32; off > 0; off >>= 1) acc[e] += __shfl_xor(acc[e], off, 64);
    }
    if (lane == 0) {
      float mx = acc[0];
#pragma unroll
      for (int e = 1; e < 8; e++) mx = fmaxf(mx, acc[e]);
      float s[8], sum = 0.f;
#pragma unroll
      for (int e = 0; e < 8; e++) { s[e] = expf(acc[e] - mx); sum += s[e]; }
      float inv = 1.f / sum;
#pragma unroll
      for (int e = 0; e < 8; e++) { s[e] *= inv; ssum_local[e] += s[e]; }
      // top-2 (strict > : ties -> lower index, matches lax.top_k)
      int i1 = 0;
#pragma unroll
      for (int e = 1; e < 8; e++) if (s[e] > s[i1]) i1 = e;
      int i2 = (i1 == 0) ? 1 : 0;
#pragma unroll
      for (int e = 0; e < 8; e++) if (e != i1 && s[e] > s[i2]) i2 = e;
      atomicAdd(&lds_top1[i1], 1);
      int r1 = atomicAdd(&lds_cnt[i1], 1);
      int r2 = atomicAdd(&lds_cnt[i2], 1);
      tk_e[lt][0] = i1; tk_r[lt][0] = r1; tk_w[lt][0] = s[i1];
      tk_e[lt][1] = i2; tk_r[lt][1] = r2; tk_w[lt][1] = s[i2];
    }
  }
  if (lane == 0) {
#pragma unroll
    for (int e = 0; e < 8; e++) lds_ssum[wave][e] = ssum_local[e];
  }
  __syncthreads();
  if (tid < 8) {
    base[tid] = atomicAdd(&counts[tid], lds_cnt[tid]);
    atomicAdd(&top1cnt[tid], lds_top1[tid]);
    atomicAdd(&ssum[tid],
              lds_ssum[0][tid] + lds_ssum[1][tid] + lds_ssum[2][tid] + lds_ssum[3][tid]);
  }
  __syncthreads();
  if (tid < GB_TOK * 2) {
    int lt = tid >> 1, k = tid & 1;
    int e = tk_e[lt][k];
    int pos = base[e] + tk_r[lt][k];
    tok_list[e * T_TOK + pos] = blockIdx.x * GB_TOK + lt;
    wgt_list[e * T_TOK + pos] = tk_w[lt][k];
  }
}

// ---------------- scan + l_aux + flat tile map (BM=128 tiles) ----------------
__global__ void scan_kernel(const int* counts, const int* top1cnt, const float* ssum,
                            int* h_off, int* tile_off, float* laux_out) {
  if (threadIdx.x == 0 && blockIdx.x == 0) {
    int off = 0, toff = 0;
    float l = 0.f;
    for (int e = 0; e < 8; e++) {
      h_off[e] = off;
      tile_off[e] = toff;
      off += counts[e];
      toff += (counts[e] + BM - 1) / BM;
      l += (ssum[e] / (float)T_TOK) * ((float)top1cnt[e] / (float)T_TOK);
    }
    tile_off[8] = toff;
    *laux_out = l * (float)NE;
  }
}

// ---------------- grouped GEMM: C = gatherA(M x K) * B^T-layout(N x K) ----------------
// 128x128 tile, BK=32, 4 waves, DOUBLE-BUFFERED LDS totaling 32 KiB -> 5 blocks/CU
// (residency r0 had) AND prefetch-before-compute (what r3 added). Per K-step: issue
// STAGE(buf^1, t+1) first, one kk of 16 MFMA on buf, ONE __syncthreads(). The vmcnt(0)
// drain waits on loads issued a full K-step earlier, and 4 co-resident blocks cover the rest.
// Swizzle (64B rows = 4 x 16B chunks): LDS slot s of row r holds global chunk s ^ ((r>>1)&3);
// read side pc = quad ^ ((lm>>1)&3). Within each 16-lane group, (row-parity x pc) covers all
// 8 bank-quads exactly twice -> 2-way aliasing = free (m136).
// Flat tile grid via tile_off prefix (no dead blocks).
// MODE 0: A = x_bf gathered via tok_list; epilogue relu(acc + b1) -> h_buf bf16 (stride N==HID)
// MODE 1: A = h_buf rows (h_off[e]+row);   epilogue atomicAdd(out[tok], w*(acc + b2))
template <int MODE>
__global__ __launch_bounds__(256, 5) void moe_gemm_kernel(
    const unsigned short* __restrict__ A_src, const unsigned short* __restrict__ B_src,
    const float* __restrict__ bias, const int* __restrict__ counts,
    const int* __restrict__ h_off, const int* __restrict__ tile_off,
    const int* __restrict__ tok_list, const float* __restrict__ wgt_list,
    unsigned short* __restrict__ h_out, float* __restrict__ out, int N, int K) {
  __shared__ unsigned short s_a[2][BM][BK];  // 16 KB
  __shared__ unsigned short s_b[2][BN][BK];  // 16 KB

  const int bt = blockIdx.y;
  if (bt >= tile_off[8]) return;
  int e = 7;
#pragma unroll
  for (int q = 6; q >= 0; q--)
    if (bt < tile_off[q + 1]) e = q;
  const int n_e = counts[e];
  const int m0 = (bt - tile_off[e]) * BM;
  const int n0 = blockIdx.x * BN;
  const int tid = threadIdx.x;

  const int lane = tid & 63;
  const int wv = tid >> 6;               // 0..3

  // ---- staging geometry (16 rows x 64B per wave-call; 2 calls each for A and B) ----
  const int srow = lane >> 2;            // row within 16-row call, 0..15
  const int g = (lane & 3) ^ ((lane >> 3) & 3);  // swizzled global 16B-chunk index (0..3)

  const unsigned short* a_g[2];
  const unsigned short* b_g[2];
#pragma unroll
  for (int c = 0; c < 2; c++) {
    int ra = wv * 32 + c * 16 + srow;             // tile row 0..127
    int gr = m0 + ra;
    int safe = (gr < n_e) ? gr : (n_e - 1);       // clamp: garbage only feeds discarded C rows
    const unsigned short* abase;
    if (MODE == 0) {
      int tok = tok_list[e * T_TOK + safe];
      abase = A_src + (size_t)tok * K;
    } else {
      abase = A_src + (size_t)(h_off[e] + safe) * K;
    }
    a_g[c] = abase + g * 8;
    b_g[c] = B_src + ((size_t)e * N + n0 + ra) * K + g * 8;
  }

  auto STAGE = [&](int buf, int kt) {
#pragma unroll
    for (int c = 0; c < 2; c++) {
      __builtin_amdgcn_global_load_lds((gbl_void*)(a_g[c] + kt),
                                       (lds_void*)&s_a[buf][wv * 32 + c * 16][0], 16, 0, 0);
      __builtin_amdgcn_global_load_lds((gbl_void*)(b_g[c] + kt),
                                       (lds_void*)&s_b[buf][wv * 32 + c * 16][0], 16, 0, 0);
    }
  };

  const int lm = lane & 15;
  const int quad = lane >> 4;
  const int pc = quad ^ ((lm >> 1) & 3);  // physical chunk for this lane's fragment
  const int wm = (wv >> 1) * 64;
  const int wn = (wv & 1) * 64;

  floatx4 acc[4][4];
#pragma unroll
  for (int mi = 0; mi < 4; mi++)
#pragma unroll
    for (int ni = 0; ni < 4; ni++) acc[mi][ni] = (floatx4){0.f, 0.f, 0.f, 0.f};

  const int NT = K / BK;
  STAGE(0, 0);
  __syncthreads();

  int cur = 0;
  for (int t = 0; t < NT; ++t) {
    if (t + 1 < NT) STAGE(cur ^ 1, (t + 1) * BK);  // issue next-tile prefetch FIRST
    {
      shortx8 af[4], bfr[4];
#pragma unroll
      for (int mi = 0; mi < 4; mi++)
        af[mi] = *reinterpret_cast<const shortx8*>(&s_a[cur][wm + mi * 16 + lm][pc << 3]);
#pragma unroll
      for (int ni = 0; ni < 4; ni++)
        bfr[ni] = *reinterpret_cast<const shortx8*>(&s_b[cur][wn + ni * 16 + lm][pc << 3]);
#pragma unroll
      for (int mi = 0; mi < 4; mi++)
#pragma unroll
        for (int ni = 0; ni < 4; ni++)
          acc[mi][ni] = __builtin_amdgcn_mfma_f32_16x16x32_bf16(af[mi], bfr[ni], acc[mi][ni], 0, 0, 0);
    }
    __syncthreads();  // one barrier per K-step: drains prefetch + guards buffer reuse
    cur ^= 1;
  }

  // epilogue: D row = quad*4 + r, col = lm (verified C/D layout)
#pragma unroll
  for (int mi = 0; mi < 4; mi++) {
#pragma unroll
    for (int r = 0; r < 4; r++) {
      int row = m0 + wm + mi * 16 + quad * 4 + r;
      if (row >= n_e) continue;
      if (MODE == 0) {
        size_t base = (size_t)(h_off[e] + row) * N;
#pragma unroll
        for (int ni = 0; ni < 4; ni++) {
          int col = n0 + wn + ni * 16 + lm;
          float v = acc[mi][ni][r] + bias[e * N + col];
          v = fmaxf(v, 0.f);
          h_out[base + col] = f2bf(v);
        }
      } else {
        int tok = tok_list[e * T_TOK + row];
        float wgt = wgt_list[e * T_TOK + row];
        size_t base = (size_t)tok * N;
#pragma unroll
        for (int ni = 0; ni < 4; ni++) {
          int col = n0 + wn + ni * 16 + lm;
          float v = wgt * (acc[mi][ni][r] + bias[e * N + col]);
          atomicAdd(&out[base + col], v);
        }
      }
    }
  }
}

extern "C" void kernel_launch(void* const* d_in, const int* in_sizes, int n_in,
                              void* d_out, int out_size, void* d_ws, size_t ws_size,
                              hipStream_t stream) {
  const float* x  = (const float*)d_in[0];
  const float* wg = (const float*)d_in[1];
  const float* w1 = (const float*)d_in[2];
  const float* b1 = (const float*)d_in[3];
  const float* w2 = (const float*)d_in[4];
  const float* b2 = (const float*)d_in[5];
  float* out = (float*)d_out;

  char* ws = (char*)d_ws;
  // ws layout (bytes), all 256-aligned; total ~151.5 MB
  int*            counts   = (int*)(ws + 0);
  int*            top1cnt  = (int*)(ws + 32);
  float*          ssum     = (float*)(ws + 64);
  int*            h_off    = (int*)(ws + 96);
  int*            tile_off = (int*)(ws + 128);   // 9 ints
  int*            tok_list = (int*)(ws + 256);
  float*          wgt_list = (float*)(ws + 262400);
  unsigned short* x_bf     = (unsigned short*)(ws + 524544);
  unsigned short* w1t      = (unsigned short*)(ws + 17301760);
  unsigned short* w2t      = (unsigned short*)(ws + 50856192);
  unsigned short* h_buf    = (unsigned short*)(ws + 84410624);

  hipMemsetAsync(ws, 0, 256, stream);
  hipMemsetAsync(d_out, 0, (size_t)out_size * sizeof(float), stream);

  dim3 tb(32, 8);
  transpose_cast_kernel<<<dim3(HID / 32, DIM / 32, NE), tb, 0, stream>>>(w1, w1t, DIM, HID);
  transpose_cast_kernel<<<dim3(DIM / 32, HID / 32, NE), tb, 0, stream>>>(w2, w2t, HID, DIM);

  gate_kernel<<<T_TOK / GB_TOK, 256, 0, stream>>>(x, wg, x_bf, counts, top1cnt, ssum,
                                                  tok_list, wgt_list);
  scan_kernel<<<1, 64, 0, stream>>>(counts, top1cnt, ssum, h_off, tile_off,
                                    out + (size_t)T_TOK * DIM);

  // max flat tiles = sum_e ceil(n_e/128) <= 16384/128 + 8 = 136
  // GEMM1: M=n_e, N=HID, K=DIM
  moe_gemm_kernel<0><<<dim3(HID / BN, 136, 1), 256, 0, stream>>>(
      x_bf, w1t, b1, counts, h_off, tile_off, tok_list, wgt_list, h_buf, nullptr, HID, DIM);
  // GEMM2: M=n_e, N=DIM, K=HID
  moe_gemm_kernel<1><<<dim3(DIM / BN, 136, 1), 256, 0, stream>>>(
      h_buf, w2t, b2, counts, h_off, tile_off, tok_list, wgt_list, nullptr, out, DIM, HID);
}

// Round 5
// 530.619 us; speedup vs baseline: 1.0382x; 1.0382x over previous
//
#include <hip/hip_runtime.h>
#include <stdint.h>

#define T_TOK 8192
#define DIM   1024
#define HID   2048
#define NE    8

#define BM 128
#define BN 128
#define BK 64

#define GB_TOK 32  // tokens per gate block

typedef float floatx4 __attribute__((ext_vector_type(4)));
typedef short shortx8 __attribute__((ext_vector_type(8)));

typedef __attribute__((address_space(3))) void       lds_void;
typedef const __attribute__((address_space(1))) void gbl_void;

__device__ __forceinline__ unsigned short f2bf(float f) {
  unsigned int u = __float_as_uint(f);
  unsigned int r = 0x7fffu + ((u >> 16) & 1u);
  return (unsigned short)((u + r) >> 16);
}

// ------------- transpose+cast: in [R][C] f32 -> out [C][R] bf16, blockIdx.z = expert -------------
__global__ __launch_bounds__(256) void transpose_cast_kernel(const float* __restrict__ in,
                                                             unsigned short* __restrict__ out,
                                                             int R, int C) {
  __shared__ float tile[32][33];
  const size_t eoff = (size_t)blockIdx.z * R * C;
  const float* ip = in + eoff;
  unsigned short* op = out + eoff;
  int c0 = blockIdx.x * 32, r0 = blockIdx.y * 32;
  int tx = threadIdx.x, ty = threadIdx.y;
#pragma unroll
  for (int i = 0; i < 4; i++)
    tile[ty + i * 8][tx] = ip[(size_t)(r0 + ty + i * 8) * C + (c0 + tx)];
  __syncthreads();
#pragma unroll
  for (int i = 0; i < 4; i++)
    op[(size_t)(c0 + ty + i * 8) * R + (r0 + tx)] = f2bf(tile[tx][ty + i * 8]);
}

// ---------------- gating: 32 tokens/block; also casts x -> bf16 ----------------
__global__ __launch_bounds__(256) void gate_kernel(const float* __restrict__ x,
                                                   const float* __restrict__ wg,
                                                   unsigned short* __restrict__ xb,
                                                   int* counts, int* top1cnt, float* ssum,
                                                   int* tok_list, float* wgt_list) {
  __shared__ int   lds_cnt[8];
  __shared__ int   lds_top1[8];
  __shared__ float lds_ssum[4][8];
  __shared__ int   tk_e[GB_TOK][2];
  __shared__ int   tk_r[GB_TOK][2];
  __shared__ float tk_w[GB_TOK][2];
  __shared__ int   base[8];

  const int tid = threadIdx.x;
  const int wave = tid >> 6;
  const int lane = tid & 63;

  if (tid < 8) { lds_cnt[tid] = 0; lds_top1[tid] = 0; }
  if (tid < 32) lds_ssum[tid >> 3][tid & 7] = 0.f;
  __syncthreads();

  float ssum_local[8];
#pragma unroll
  for (int e = 0; e < 8; e++) ssum_local[e] = 0.f;

  for (int it = 0; it < GB_TOK / 4; it++) {
    const int lt = it * 4 + wave;
    const int t = blockIdx.x * GB_TOK + lt;

    float acc[8];
#pragma unroll
    for (int e = 0; e < 8; e++) acc[e] = 0.f;
    const float* xr = x + (size_t)t * DIM;
    unsigned short* xw = xb + (size_t)t * DIM;
#pragma unroll
    for (int i = 0; i < 16; i++) {
      int d = i * 64 + lane;
      float xv = xr[d];
      xw[d] = f2bf(xv);  // fused f32->bf16 cast
      const float4* wr = reinterpret_cast<const float4*>(wg + d * 8);
      float4 w0 = wr[0], w1 = wr[1];
      acc[0] += xv * w0.x; acc[1] += xv * w0.y; acc[2] += xv * w0.z; acc[3] += xv * w0.w;
      acc[4] += xv * w1.x; acc[5] += xv * w1.y; acc[6] += xv * w1.z; acc[7] += xv * w1.w;
    }
#pragma unroll
    for (int e = 0; e < 8; e++) {
#pragma unroll
      for (int off = 32; off > 0; off >>= 1) acc[e] += __shfl_xor(acc[e], off, 64);
    }
    if (lane == 0) {
      float mx = acc[0];
#pragma unroll
      for (int e = 1; e < 8; e++) mx = fmaxf(mx, acc[e]);
      float s[8], sum = 0.f;
#pragma unroll
      for (int e = 0; e < 8; e++) { s[e] = expf(acc[e] - mx); sum += s[e]; }
      float inv = 1.f / sum;
#pragma unroll
      for (int e = 0; e < 8; e++) { s[e] *= inv; ssum_local[e] += s[e]; }
      // top-2 (strict > : ties -> lower index, matches lax.top_k)
      int i1 = 0;
#pragma unroll
      for (int e = 1; e < 8; e++) if (s[e] > s[i1]) i1 = e;
      int i2 = (i1 == 0) ? 1 : 0;
#pragma unroll
      for (int e = 0; e < 8; e++) if (e != i1 && s[e] > s[i2]) i2 = e;
      atomicAdd(&lds_top1[i1], 1);
      int r1 = atomicAdd(&lds_cnt[i1], 1);
      int r2 = atomicAdd(&lds_cnt[i2], 1);
      tk_e[lt][0] = i1; tk_r[lt][0] = r1; tk_w[lt][0] = s[i1];
      tk_e[lt][1] = i2; tk_r[lt][1] = r2; tk_w[lt][1] = s[i2];
    }
  }
  if (lane == 0) {
#pragma unroll
    for (int e = 0; e < 8; e++) lds_ssum[wave][e] = ssum_local[e];
  }
  __syncthreads();
  if (tid < 8) {
    base[tid] = atomicAdd(&counts[tid], lds_cnt[tid]);
    atomicAdd(&top1cnt[tid], lds_top1[tid]);
    atomicAdd(&ssum[tid],
              lds_ssum[0][tid] + lds_ssum[1][tid] + lds_ssum[2][tid] + lds_ssum[3][tid]);
  }
  __syncthreads();
  if (tid < GB_TOK * 2) {
    int lt = tid >> 1, k = tid & 1;
    int e = tk_e[lt][k];
    int pos = base[e] + tk_r[lt][k];
    tok_list[e * T_TOK + pos] = blockIdx.x * GB_TOK + lt;
    wgt_list[e * T_TOK + pos] = tk_w[lt][k];
  }
}

// ---------------- scan + l_aux + flat tile map (BM=128 tiles) ----------------
__global__ void scan_kernel(const int* counts, const int* top1cnt, const float* ssum,
                            int* h_off, int* tile_off, float* laux_out) {
  if (threadIdx.x == 0 && blockIdx.x == 0) {
    int off = 0, toff = 0;
    float l = 0.f;
    for (int e = 0; e < 8; e++) {
      h_off[e] = off;
      tile_off[e] = toff;
      off += counts[e];
      toff += (counts[e] + BM - 1) / BM;
      l += (ssum[e] / (float)T_TOK) * ((float)top1cnt[e] / (float)T_TOK);
    }
    tile_off[8] = toff;
    *laux_out = l * (float)NE;
  }
}

// ---------------- grouped GEMM: C = gatherA(M x K) * B^T-layout(N x K) ----------------
// 128x128 tile, BK=64, 4 waves, double-buffered LDS (64 KiB, 2 blocks/CU).
// COUNTED-VMCNT NEVER-DRAIN schedule (T4; the single change vs round-3):
//   prologue: STAGE(tile0), STAGE(tile1)            -> 16 loads/thread in flight
//   iter t:   s_waitcnt vmcnt(8)                     -> tile t complete (issued 2 iters ago),
//                                                      tile t+1's 8 loads STAY in flight
//             s_barrier ; compute buf[t&1] ; s_barrier
//             STAGE(buf[t&1], tile t+2)              -> back to 16 in flight
// In-flight DMA never drops below 8 loads/thread (~32 KB/block), vs __syncthreads' vmcnt(0)
// drain-to-zero every K-step that capped effective fetch at ~2 TB/s (duty-cycle bound).
// Ledger: own-thread vmcnt(8) before the barrier => after the barrier ALL threads' tile-t
// DMA has landed; the post-compute barrier guards refill vs readers. Tail peels to vmcnt(0).
// Staging/swizzle/read geometry identical to verified r0/r3 (0 bank conflicts).
// MODE 0: A = x_bf gathered via tok_list; epilogue relu(acc + b1) -> h_buf bf16 (stride N==HID)
// MODE 1: A = h_buf rows (h_off[e]+row);   epilogue atomicAdd(out[tok], w*(acc + b2))
template <int MODE>
__global__ __launch_bounds__(256, 2) void moe_gemm_kernel(
    const unsigned short* __restrict__ A_src, const unsigned short* __restrict__ B_src,
    const float* __restrict__ bias, const int* __restrict__ counts,
    const int* __restrict__ h_off, const int* __restrict__ tile_off,
    const int* __restrict__ tok_list, const float* __restrict__ wgt_list,
    unsigned short* __restrict__ h_out, float* __restrict__ out, int N, int K) {
  __shared__ unsigned short s_a[2][BM][BK];  // 32 KB
  __shared__ unsigned short s_b[2][BN][BK];  // 32 KB

  const int bt = blockIdx.y;
  if (bt >= tile_off[8]) return;
  int e = 7;
#pragma unroll
  for (int q = 6; q >= 0; q--)
    if (bt < tile_off[q + 1]) e = q;
  const int n_e = counts[e];
  const int m0 = (bt - tile_off[e]) * BM;
  const int n0 = blockIdx.x * BN;
  const int tid = threadIdx.x;

  const int lane = tid & 63;
  const int wv = tid >> 6;               // 0..3
  const int lrow = lane >> 3;            // 0..7  (row within 8-row DMA call)
  const int lchk = (lane & 7) ^ lrow;    // XOR-swizzled global 16B chunk index

  // per-lane global source pointers; 4 staging calls each for A and B (8 rows per call/wave)
  const unsigned short* a_g[4];
  const unsigned short* b_g[4];
#pragma unroll
  for (int c = 0; c < 4; c++) {
    int ra = wv * 32 + c * 8 + lrow;              // tile row 0..127
    int gr = m0 + ra;
    int safe = (gr < n_e) ? gr : (n_e - 1);       // clamp: garbage only feeds discarded C rows
    const unsigned short* abase;
    if (MODE == 0) {
      int tok = tok_list[e * T_TOK + safe];
      abase = A_src + (size_t)tok * K;
    } else {
      abase = A_src + (size_t)(h_off[e] + safe) * K;
    }
    a_g[c] = abase + lchk * 8;
    b_g[c] = B_src + ((size_t)e * N + n0 + ra) * K + lchk * 8;
  }

  auto STAGE = [&](int buf, int kt) {
#pragma unroll
    for (int c = 0; c < 4; c++) {
      __builtin_amdgcn_global_load_lds((gbl_void*)(a_g[c] + kt),
                                       (lds_void*)&s_a[buf][wv * 32 + c * 8][0], 16, 0, 0);
      __builtin_amdgcn_global_load_lds((gbl_void*)(b_g[c] + kt),
                                       (lds_void*)&s_b[buf][wv * 32 + c * 8][0], 16, 0, 0);
    }
  };

  const int lm = lane & 15;
  const int quad = lane >> 4;
  const int r7 = lm & 7;                 // == row&7 for all fragment rows
  const int wm = (wv >> 1) * 64;
  const int wn = (wv & 1) * 64;

  floatx4 acc[4][4];
#pragma unroll
  for (int mi = 0; mi < 4; mi++)
#pragma unroll
    for (int ni = 0; ni < 4; ni++) acc[mi][ni] = (floatx4){0.f, 0.f, 0.f, 0.f};

  const int NT = K / BK;  // 16 or 32

  // prologue: two tiles in flight
  STAGE(0, 0);
  STAGE(1, BK);

  int cur = 0;
  for (int t = 0; t < NT; ++t) {
    if (t + 1 < NT)
      asm volatile("s_waitcnt vmcnt(8)" ::: "memory");  // tile t done; t+1 stays in flight
    else
      asm volatile("s_waitcnt vmcnt(0)" ::: "memory");  // last tile: full drain
    __builtin_amdgcn_s_barrier();
    asm volatile("" ::: "memory");
#pragma unroll
    for (int kk = 0; kk < 2; kk++) {
      const int pc = ((kk << 2) + quad) ^ r7;      // physical chunk for this lane's fragment
      shortx8 af[4], bfr[4];
#pragma unroll
      for (int mi = 0; mi < 4; mi++)
        af[mi] = *reinterpret_cast<const shortx8*>(&s_a[cur][wm + mi * 16 + lm][pc << 3]);
#pragma unroll
      for (int ni = 0; ni < 4; ni++)
        bfr[ni] = *reinterpret_cast<const shortx8*>(&s_b[cur][wn + ni * 16 + lm][pc << 3]);
#pragma unroll
      for (int mi = 0; mi < 4; mi++)
#pragma unroll
        for (int ni = 0; ni < 4; ni++)
          acc[mi][ni] = __builtin_amdgcn_mfma_f32_16x16x32_bf16(af[mi], bfr[ni], acc[mi][ni], 0, 0, 0);
    }
    asm volatile("" ::: "memory");
    __builtin_amdgcn_s_barrier();                  // all waves done reading buf[cur]
    asm volatile("" ::: "memory");
    if (t + 2 < NT) STAGE(cur, (t + 2) * BK);      // refill the buffer just consumed
    cur ^= 1;
  }

  // epilogue: D row = quad*4 + r, col = lm (verified C/D layout)
#pragma unroll
  for (int mi = 0; mi < 4; mi++) {
#pragma unroll
    for (int r = 0; r < 4; r++) {
      int row = m0 + wm + mi * 16 + quad * 4 + r;
      if (row >= n_e) continue;
      if (MODE == 0) {
        size_t base = (size_t)(h_off[e] + row) * N;
#pragma unroll
        for (int ni = 0; ni < 4; ni++) {
          int col = n0 + wn + ni * 16 + lm;
          float v = acc[mi][ni][r] + bias[e * N + col];
          v = fmaxf(v, 0.f);
          h_out[base + col] = f2bf(v);
        }
      } else {
        int tok = tok_list[e * T_TOK + row];
        float wgt = wgt_list[e * T_TOK + row];
        size_t base = (size_t)tok * N;
#pragma unroll
        for (int ni = 0; ni < 4; ni++) {
          int col = n0 + wn + ni * 16 + lm;
          float v = wgt * (acc[mi][ni][r] + bias[e * N + col]);
          atomicAdd(&out[base + col], v);
        }
      }
    }
  }
}

extern "C" void kernel_launch(void* const* d_in, const int* in_sizes, int n_in,
                              void* d_out, int out_size, void* d_ws, size_t ws_size,
                              hipStream_t stream) {
  const float* x  = (const float*)d_in[0];
  const float* wg = (const float*)d_in[1];
  const float* w1 = (const float*)d_in[2];
  const float* b1 = (const float*)d_in[3];
  const float* w2 = (const float*)d_in[4];
  const float* b2 = (const float*)d_in[5];
  float* out = (float*)d_out;

  char* ws = (char*)d_ws;
  // ws layout (bytes), all 256-aligned; total ~151.5 MB
  int*            counts   = (int*)(ws + 0);
  int*            top1cnt  = (int*)(ws + 32);
  float*          ssum     = (float*)(ws + 64);
  int*            h_off    = (int*)(ws + 96);
  int*            tile_off = (int*)(ws + 128);   // 9 ints
  int*            tok_list = (int*)(ws + 256);
  float*          wgt_list = (float*)(ws + 262400);
  unsigned short* x_bf     = (unsigned short*)(ws + 524544);
  unsigned short* w1t      = (unsigned short*)(ws + 17301760);
  unsigned short* w2t      = (unsigned short*)(ws + 50856192);
  unsigned short* h_buf    = (unsigned short*)(ws + 84410624);

  hipMemsetAsync(ws, 0, 256, stream);
  hipMemsetAsync(d_out, 0, (size_t)out_size * sizeof(float), stream);

  dim3 tb(32, 8);
  transpose_cast_kernel<<<dim3(HID / 32, DIM / 32, NE), tb, 0, stream>>>(w1, w1t, DIM, HID);
  transpose_cast_kernel<<<dim3(DIM / 32, HID / 32, NE), tb, 0, stream>>>(w2, w2t, HID, DIM);

  gate_kernel<<<T_TOK / GB_TOK, 256, 0, stream>>>(x, wg, x_bf, counts, top1cnt, ssum,
                                                  tok_list, wgt_list);
  scan_kernel<<<1, 64, 0, stream>>>(counts, top1cnt, ssum, h_off, tile_off,
                                    out + (size_t)T_TOK * DIM);

  // max flat tiles = sum_e ceil(n_e/128) <= 16384/128 + 8 = 136
  // GEMM1: M=n_e, N=HID, K=DIM
  moe_gemm_kernel<0><<<dim3(HID / BN, 136, 1), 256, 0, stream>>>(
      x_bf, w1t, b1, counts, h_off, tile_off, tok_list, wgt_list, h_buf, nullptr, HID, DIM);
  // GEMM2: M=n_e, N=DIM, K=HID
  moe_gemm_kernel<1><<<dim3(DIM / BN, 136, 1), 256, 0, stream>>>(
      h_buf, w2t, b2, counts, h_off, tile_off, tok_list, wgt_list, nullptr, out, DIM, HID);
}

// Round 6
// 461.111 us; speedup vs baseline: 1.1947x; 1.1507x over previous
//
#include <hip/hip_runtime.h>
#include <stdint.h>

#define T_TOK 8192
#define DIM   1024
#define HID   2048
#define NE    8

#define BM 128
#define BN 128
#define BK 64

#define GB_TOK 32  // tokens per gate block

typedef float floatx4 __attribute__((ext_vector_type(4)));
typedef short shortx8 __attribute__((ext_vector_type(8)));

typedef __attribute__((address_space(3))) void       lds_void;
typedef const __attribute__((address_space(1))) void gbl_void;

__device__ __forceinline__ unsigned short f2bf(float f) {
  unsigned int u = __float_as_uint(f);
  unsigned int r = 0x7fffu + ((u >> 16) & 1u);
  return (unsigned short)((u + r) >> 16);
}

// ------------- transpose+cast: in [R][C] f32 -> out [C][R] bf16, blockIdx.z = expert -------------
__global__ __launch_bounds__(256) void transpose_cast_kernel(const float* __restrict__ in,
                                                             unsigned short* __restrict__ out,
                                                             int R, int C) {
  __shared__ float tile[32][33];
  const size_t eoff = (size_t)blockIdx.z * R * C;
  const float* ip = in + eoff;
  unsigned short* op = out + eoff;
  int c0 = blockIdx.x * 32, r0 = blockIdx.y * 32;
  int tx = threadIdx.x, ty = threadIdx.y;
#pragma unroll
  for (int i = 0; i < 4; i++)
    tile[ty + i * 8][tx] = ip[(size_t)(r0 + ty + i * 8) * C + (c0 + tx)];
  __syncthreads();
#pragma unroll
  for (int i = 0; i < 4; i++)
    op[(size_t)(c0 + ty + i * 8) * R + (r0 + tx)] = f2bf(tile[tx][ty + i * 8]);
}

// ---------------- gating: 32 tokens/block; also casts x -> bf16 ----------------
__global__ __launch_bounds__(256) void gate_kernel(const float* __restrict__ x,
                                                   const float* __restrict__ wg,
                                                   unsigned short* __restrict__ xb,
                                                   int* counts, int* top1cnt, float* ssum,
                                                   int* tok_list, float* wgt_list) {
  __shared__ int   lds_cnt[8];
  __shared__ int   lds_top1[8];
  __shared__ float lds_ssum[4][8];
  __shared__ int   tk_e[GB_TOK][2];
  __shared__ int   tk_r[GB_TOK][2];
  __shared__ float tk_w[GB_TOK][2];
  __shared__ int   base[8];

  const int tid = threadIdx.x;
  const int wave = tid >> 6;
  const int lane = tid & 63;

  if (tid < 8) { lds_cnt[tid] = 0; lds_top1[tid] = 0; }
  if (tid < 32) lds_ssum[tid >> 3][tid & 7] = 0.f;
  __syncthreads();

  float ssum_local[8];
#pragma unroll
  for (int e = 0; e < 8; e++) ssum_local[e] = 0.f;

  for (int it = 0; it < GB_TOK / 4; it++) {
    const int lt = it * 4 + wave;
    const int t = blockIdx.x * GB_TOK + lt;

    float acc[8];
#pragma unroll
    for (int e = 0; e < 8; e++) acc[e] = 0.f;
    const float* xr = x + (size_t)t * DIM;
    unsigned short* xw = xb + (size_t)t * DIM;
#pragma unroll
    for (int i = 0; i < 16; i++) {
      int d = i * 64 + lane;
      float xv = xr[d];
      xw[d] = f2bf(xv);  // fused f32->bf16 cast
      const float4* wr = reinterpret_cast<const float4*>(wg + d * 8);
      float4 w0 = wr[0], w1 = wr[1];
      acc[0] += xv * w0.x; acc[1] += xv * w0.y; acc[2] += xv * w0.z; acc[3] += xv * w0.w;
      acc[4] += xv * w1.x; acc[5] += xv * w1.y; acc[6] += xv * w1.z; acc[7] += xv * w1.w;
    }
#pragma unroll
    for (int e = 0; e < 8; e++) {
#pragma unroll
      for (int off = 32; off > 0; off >>= 1) acc[e] += __shfl_xor(acc[e], off, 64);
    }
    if (lane == 0) {
      float mx = acc[0];
#pragma unroll
      for (int e = 1; e < 8; e++) mx = fmaxf(mx, acc[e]);
      float s[8], sum = 0.f;
#pragma unroll
      for (int e = 0; e < 8; e++) { s[e] = expf(acc[e] - mx); sum += s[e]; }
      float inv = 1.f / sum;
#pragma unroll
      for (int e = 0; e < 8; e++) { s[e] *= inv; ssum_local[e] += s[e]; }
      // top-2 (strict > : ties -> lower index, matches lax.top_k)
      int i1 = 0;
#pragma unroll
      for (int e = 1; e < 8; e++) if (s[e] > s[i1]) i1 = e;
      int i2 = (i1 == 0) ? 1 : 0;
#pragma unroll
      for (int e = 0; e < 8; e++) if (e != i1 && s[e] > s[i2]) i2 = e;
      atomicAdd(&lds_top1[i1], 1);
      int r1 = atomicAdd(&lds_cnt[i1], 1);
      int r2 = atomicAdd(&lds_cnt[i2], 1);
      tk_e[lt][0] = i1; tk_r[lt][0] = r1; tk_w[lt][0] = s[i1];
      tk_e[lt][1] = i2; tk_r[lt][1] = r2; tk_w[lt][1] = s[i2];
    }
  }
  if (lane == 0) {
#pragma unroll
    for (int e = 0; e < 8; e++) lds_ssum[wave][e] = ssum_local[e];
  }
  __syncthreads();
  if (tid < 8) {
    base[tid] = atomicAdd(&counts[tid], lds_cnt[tid]);
    atomicAdd(&top1cnt[tid], lds_top1[tid]);
    atomicAdd(&ssum[tid],
              lds_ssum[0][tid] + lds_ssum[1][tid] + lds_ssum[2][tid] + lds_ssum[3][tid]);
  }
  __syncthreads();
  if (tid < GB_TOK * 2) {
    int lt = tid >> 1, k = tid & 1;
    int e = tk_e[lt][k];
    int pos = base[e] + tk_r[lt][k];
    tok_list[e * T_TOK + pos] = blockIdx.x * GB_TOK + lt;
    wgt_list[e * T_TOK + pos] = tk_w[lt][k];
  }
}

// ---------------- scan + l_aux + flat tile map (BM=128 tiles) ----------------
__global__ void scan_kernel(const int* counts, const int* top1cnt, const float* ssum,
                            int* h_off, int* tile_off, float* laux_out) {
  if (threadIdx.x == 0 && blockIdx.x == 0) {
    int off = 0, toff = 0;
    float l = 0.f;
    for (int e = 0; e < 8; e++) {
      h_off[e] = off;
      tile_off[e] = toff;
      off += counts[e];
      toff += (counts[e] + BM - 1) / BM;
      l += (ssum[e] / (float)T_TOK) * ((float)top1cnt[e] / (float)T_TOK);
    }
    tile_off[8] = toff;
    *laux_out = l * (float)NE;
  }
}

// ---------------- grouped GEMM: C = gatherA(M x K) * B^T-layout(N x K) ----------------
// Structure = measured-best r0: 128x128 tile, BK=64, 4 waves, SINGLE 32 KB LDS buffer,
// 2 barriers/K-step, ~4 blocks/CU.
// NEW (T1): 1-D grid + bijective chunked XCD swizzle. HW assigns linear block id round-robin
// to the 8 XCDs (id%8); remap wg=(bid&7)*CPX+(bid>>3) so each XCD executes a CONTIGUOUS
// range of (m-tile, n-tile) pairs, n-tile fastest. Effect: an A-panel is fetched by exactly
// one XCD (its 16 n-blocks are chunk-adjacent), and the XCD's B working set ~= one expert's
// 4 MB panel ~= its private L2. Theory: the staging path is L2-miss-LATENCY capped
// (outstanding-line budget x 128B / latency ~= observed 10 B/cyc/CU; m97 hit 22 B/cyc when
// L2-hot). Better locality -> lower latency -> higher DMA stream rate. Discriminator:
// FETCH_SIZE 283 MB -> ~100-160 MB.
// global_load_lds width=16 staging with XOR-swizzled chunk placement (verified 0 conflicts).
// MODE 0: A = x_bf gathered via tok_list; epilogue relu(acc + b1) -> h_buf bf16 (stride N==HID)
// MODE 1: A = h_buf rows (h_off[e]+row);   epilogue atomicAdd(out[tok], w*(acc + b2))
template <int MODE>
__global__ __launch_bounds__(256, 4) void moe_gemm_kernel(
    const unsigned short* __restrict__ A_src, const unsigned short* __restrict__ B_src,
    const float* __restrict__ bias, const int* __restrict__ counts,
    const int* __restrict__ h_off, const int* __restrict__ tile_off,
    const int* __restrict__ tok_list, const float* __restrict__ wgt_list,
    unsigned short* __restrict__ h_out, float* __restrict__ out, int N, int K) {
  __shared__ unsigned short s_a[BM][BK];   // 16 KB
  __shared__ unsigned short s_b[BN][BK];   // 16 KB

  // ---- chunked XCD swizzle (bijective: grid size is a multiple of 8) ----
  const int ntx = N / BN;            // 16 (GEMM1) or 8 (GEMM2)
  const int cpx = ntx * 17;          // blocks per XCD chunk = ntx * 136 / 8
  const int bid = blockIdx.x;
  const int wg  = (bid & 7) * cpx + (bid >> 3);
  const int bt  = wg / ntx;          // flat M-tile
  const int nt  = wg - bt * ntx;     // N-tile (fastest within chunk)

  if (bt >= tile_off[8]) return;
  int e = 7;
#pragma unroll
  for (int q = 6; q >= 0; q--)
    if (bt < tile_off[q + 1]) e = q;
  const int n_e = counts[e];
  const int m0 = (bt - tile_off[e]) * BM;
  const int n0 = nt * BN;
  const int tid = threadIdx.x;

  const int lane = tid & 63;
  const int wv = tid >> 6;               // 0..3
  const int lrow = lane >> 3;            // 0..7  (row within 8-row DMA call)
  const int lchk = (lane & 7) ^ lrow;    // XOR-swizzled global 16B chunk index

  // per-lane global source pointers + wave-uniform LDS dests, 4 calls each for A and B
  const unsigned short* a_g[4];
  const unsigned short* b_g[4];
  lds_void* a_l[4];
  lds_void* b_l[4];
#pragma unroll
  for (int c = 0; c < 4; c++) {
    int ra = wv * 32 + c * 8 + lrow;              // tile row 0..127
    int gr = m0 + ra;
    int safe = (gr < n_e) ? gr : (n_e - 1);       // clamp: garbage only feeds discarded C rows
    const unsigned short* abase;
    if (MODE == 0) {
      int tok = tok_list[e * T_TOK + safe];
      abase = A_src + (size_t)tok * K;
    } else {
      abase = A_src + (size_t)(h_off[e] + safe) * K;
    }
    a_g[c] = abase + lchk * 8;
    b_g[c] = B_src + ((size_t)e * N + n0 + ra) * K + lchk * 8;
    a_l[c] = (lds_void*)&s_a[wv * 32 + c * 8][0];
    b_l[c] = (lds_void*)&s_b[wv * 32 + c * 8][0];
  }

  const int lm = lane & 15;
  const int quad = lane >> 4;
  const int r7 = lm & 7;                 // == row&7 for all fragment rows
  const int wm = (wv >> 1) * 64;
  const int wn = (wv & 1) * 64;

  floatx4 acc[4][4];
#pragma unroll
  for (int mi = 0; mi < 4; mi++)
#pragma unroll
    for (int ni = 0; ni < 4; ni++) acc[mi][ni] = (floatx4){0.f, 0.f, 0.f, 0.f};

  for (int kt = 0; kt < K; kt += BK) {
#pragma unroll
    for (int c = 0; c < 4; c++) {
      __builtin_amdgcn_global_load_lds((gbl_void*)(a_g[c] + kt), a_l[c], 16, 0, 0);
      __builtin_amdgcn_global_load_lds((gbl_void*)(b_g[c] + kt), b_l[c], 16, 0, 0);
    }
    __syncthreads();
#pragma unroll
    for (int kk = 0; kk < 2; kk++) {
      const int pc = ((kk << 2) + quad) ^ r7;   // physical chunk for this lane's fragment
      shortx8 af[4], bfr[4];
#pragma unroll
      for (int mi = 0; mi < 4; mi++)
        af[mi] = *reinterpret_cast<const shortx8*>(&s_a[wm + mi * 16 + lm][pc << 3]);
#pragma unroll
      for (int ni = 0; ni < 4; ni++)
        bfr[ni] = *reinterpret_cast<const shortx8*>(&s_b[wn + ni * 16 + lm][pc << 3]);
#pragma unroll
      for (int mi = 0; mi < 4; mi++)
#pragma unroll
        for (int ni = 0; ni < 4; ni++)
          acc[mi][ni] = __builtin_amdgcn_mfma_f32_16x16x32_bf16(af[mi], bfr[ni], acc[mi][ni], 0, 0, 0);
    }
    __syncthreads();
  }

  // epilogue: D row = quad*4 + r, col = lm (verified C/D layout)
#pragma unroll
  for (int mi = 0; mi < 4; mi++) {
#pragma unroll
    for (int r = 0; r < 4; r++) {
      int row = m0 + wm + mi * 16 + quad * 4 + r;
      if (row >= n_e) continue;
      if (MODE == 0) {
        size_t base = (size_t)(h_off[e] + row) * N;
#pragma unroll
        for (int ni = 0; ni < 4; ni++) {
          int col = n0 + wn + ni * 16 + lm;
          float v = acc[mi][ni][r] + bias[e * N + col];
          v = fmaxf(v, 0.f);
          h_out[base + col] = f2bf(v);
        }
      } else {
        int tok = tok_list[e * T_TOK + row];
        float wgt = wgt_list[e * T_TOK + row];
        size_t base = (size_t)tok * N;
#pragma unroll
        for (int ni = 0; ni < 4; ni++) {
          int col = n0 + wn + ni * 16 + lm;
          float v = wgt * (acc[mi][ni][r] + bias[e * N + col]);
          atomicAdd(&out[base + col], v);
        }
      }
    }
  }
}

extern "C" void kernel_launch(void* const* d_in, const int* in_sizes, int n_in,
                              void* d_out, int out_size, void* d_ws, size_t ws_size,
                              hipStream_t stream) {
  const float* x  = (const float*)d_in[0];
  const float* wg = (const float*)d_in[1];
  const float* w1 = (const float*)d_in[2];
  const float* b1 = (const float*)d_in[3];
  const float* w2 = (const float*)d_in[4];
  const float* b2 = (const float*)d_in[5];
  float* out = (float*)d_out;

  char* ws = (char*)d_ws;
  // ws layout (bytes), all 256-aligned; total ~151.5 MB
  int*            counts   = (int*)(ws + 0);
  int*            top1cnt  = (int*)(ws + 32);
  float*          ssum     = (float*)(ws + 64);
  int*            h_off    = (int*)(ws + 96);
  int*            tile_off = (int*)(ws + 128);   // 9 ints
  int*            tok_list = (int*)(ws + 256);
  float*          wgt_list = (float*)(ws + 262400);
  unsigned short* x_bf     = (unsigned short*)(ws + 524544);
  unsigned short* w1t      = (unsigned short*)(ws + 17301760);
  unsigned short* w2t      = (unsigned short*)(ws + 50856192);
  unsigned short* h_buf    = (unsigned short*)(ws + 84410624);

  hipMemsetAsync(ws, 0, 256, stream);
  hipMemsetAsync(d_out, 0, (size_t)out_size * sizeof(float), stream);

  dim3 tb(32, 8);
  transpose_cast_kernel<<<dim3(HID / 32, DIM / 32, NE), tb, 0, stream>>>(w1, w1t, DIM, HID);
  transpose_cast_kernel<<<dim3(DIM / 32, HID / 32, NE), tb, 0, stream>>>(w2, w2t, HID, DIM);

  gate_kernel<<<T_TOK / GB_TOK, 256, 0, stream>>>(x, wg, x_bf, counts, top1cnt, ssum,
                                                  tok_list, wgt_list);
  scan_kernel<<<1, 64, 0, stream>>>(counts, top1cnt, ssum, h_off, tile_off,
                                    out + (size_t)T_TOK * DIM);

  // 1-D grids, multiples of 8 for the bijective XCD chunk swizzle:
  // GEMM1: 16 n-tiles x 136 flat m-tiles = 2176; GEMM2: 8 x 136 = 1088.
  moe_gemm_kernel<0><<<dim3((HID / BN) * 136), 256, 0, stream>>>(
      x_bf, w1t, b1, counts, h_off, tile_off, tok_list, wgt_list, h_buf, nullptr, HID, DIM);
  moe_gemm_kernel<1><<<dim3((DIM / BN) * 136), 256, 0, stream>>>(
      h_buf, w2t, b2, counts, h_off, tile_off, tok_list, wgt_list, nullptr, out, DIM, HID);
}